// Round 5
// baseline (61.622 us; speedup 1.0000x reference)
//
#include <hip/hip_runtime.h>
#include <hip/hip_bf16.h>

#define NN 16384
#define DD 64
#define TT 128                 // 128-col tiles
#define NB 64                  // 256-row bands
#define NUNITS 4160            // sum_I (128 - 2I), I=0..63
#define NBLK 1024              // 4 blocks/CU (32 KB LDS each) -> all resident
#define NPOSB (NN/4)           // norm blocks (4 rows each)
#define SCREEN_T 0.49f         // hinge>0 needs gram > ~0.5-3e-5; margin 1e-2

constexpr float F_EPS_PD   = 1e-6f;
constexpr float F_EPS_NORM = 1e-6f;

using bf16x8 = __attribute__((ext_vector_type(8))) short;
using f32x4  = __attribute__((ext_vector_type(4))) float;
typedef __attribute__((address_space(1))) const unsigned int gu32_t;
typedef __attribute__((address_space(3))) unsigned int       lu32_t;

__device__ __forceinline__ float wave_sum_f(float v) {
    #pragma unroll
    for (int o = 32; o >= 1; o >>= 1) v += __shfl_xor(v, o);
    return v;
}

// unit offset of band I: off(I) = I*(129 - I)
__device__ __forceinline__ int band_off(int I) { return I * (129 - I); }

// ---------------------------------------------------------------------------
// Kernel 1: per-row normalize + bf16 copy + u/vc terms + exact fp32 pos loss.
//   u[i]  = sq_i + 2*eps*s_i
//   vc[j] = sq_j - 2*eps*s_j + D*eps*eps      (d2 = u_i + vc_j - 2*gram)
// ---------------------------------------------------------------------------
__global__ __launch_bounds__(256) void norm_kernel(
    const float* __restrict__ emb, const int* __restrict__ pidx,
    float* __restrict__ u, float* __restrict__ vc,
    __hip_bfloat16* __restrict__ ebf, float* __restrict__ posP) {
    int w    = threadIdx.x >> 6;
    int row  = blockIdx.x * 4 + w;
    int lane = threadIdx.x & 63;
    int j    = pidx[row];
    float x  = emb[(size_t)row * DD + lane];
    float xj = emb[(size_t)j   * DD + lane];

    float n2  = wave_sum_f(x * x);
    float sx  = wave_sum_f(x);
    float n2j = wave_sum_f(xj * xj);
    float sxj = wave_sum_f(xj);
    float dot = wave_sum_f(x * xj);

    float m  = fmaxf(sqrtf(n2),  F_EPS_NORM);
    float mj = fmaxf(sqrtf(n2j), F_EPS_NORM);
    ebf[(size_t)row * DD + lane] = __float2bfloat16(x / m);

    __shared__ float spos[4];
    if (lane == 0) {
        float sq  = n2 / (m * m);
        float sqj = n2j / (mj * mj);
        float s   = sx / m;
        float sj  = sxj / mj;
        float g   = dot / (m * mj);
        u[row]  = sq + 2.0f * F_EPS_PD * s;
        vc[row] = sq - 2.0f * F_EPS_PD * s + (float)DD * F_EPS_PD * F_EPS_PD;
        float d2p = sq + sqj - 2.0f * g + 2.0f * F_EPS_PD * (s - sj)
                  + (float)DD * F_EPS_PD * F_EPS_PD;
        spos[w] = fmaxf(d2p, 0.0f);
    }
    __syncthreads();
    if (threadIdx.x == 0)
        posP[blockIdx.x] = spos[0] + spos[1] + spos[2] + spos[3];
}

// ---------------------------------------------------------------------------
// Kernel 2: persistent blocks over (band I of 256 rows, col-tile tj of 128).
// Units: tj in [2I, 128) -> 4160. Wave w owns 64 rows (4 strips of 16):
// per t-iter 2 ds_read_b128 feed 8 MFMA (R=64 doubles MFMA:LDS ratio vs r4).
// Per-wave weight: own row-tile rt=2I+(w>>1); tj==rt diag (1), tj>rt upper
// (2), tj<rt lower (0, skipped). B staged in LDS via global_load_lds,
// 2-phase double buffer, chunk-major [8][128][8] (conflict-validated r4).
// Screen: hinge possible only if gram > ~0.5; exact math on rare (~2%) path.
// ---------------------------------------------------------------------------
__global__ __launch_bounds__(256, 4) void pair_kernel(
    const short* __restrict__ ebf, const float* __restrict__ u,
    const float* __restrict__ vc, const int* __restrict__ lab,
    float* __restrict__ negP) {
    __shared__ short lbs[2][8192];   // 2 x 16 KB: [chunk(8)][row(128)][8 bf16]
    int tid  = threadIdx.x;
    int w    = tid >> 6;
    int lane = tid & 63;
    int lrow = lane & 15, lkh = lane >> 4;

    int ks = (int)(((long long)blockIdx.x * NUNITS) / NBLK);
    int ke = (int)(((long long)(blockIdx.x + 1) * NUNITS) / NBLK);

    // decode ks -> (I, tj)
    int I = (int)((129.0f - sqrtf(16641.0f - 4.0f * (float)ks)) * 0.5f);
    I = I < 0 ? 0 : (I > NB - 1 ? NB - 1 : I);
    while (band_off(I) > ks) --I;
    while (I < NB - 1 && band_off(I + 1) <= ks) ++I;
    int tj = 2 * I + (ks - band_off(I));

    int srr  = (w & 1) * 64 + lane;   // staging source row within col-tile
    int wsel = w >> 1;

    bf16x8 a[4][2];                   // 4 row-strips x 2 K-halves (64 rows)
    int rowbase = I * 256 + w * 64;
    float hacc = 0.0f;
    int cur = 0;

    // ---- stage tile tj into buf 0; load A(band I) ----
    {
        const short* bt = ebf + (size_t)tj * (128 * DD);
        #pragma unroll
        for (int q = 0; q < 4; ++q) {
            int chunk = 2 * q + wsel;
            __builtin_amdgcn_global_load_lds(
                (gu32_t*)(const void*)(bt + (size_t)srr * DD + chunk * 8),
                (lu32_t*)(void*)&lbs[0][q * 2048 + w * 512], 16, 0, 0);
        }
        #pragma unroll
        for (int s = 0; s < 4; ++s) {
            const short* ab = ebf + (size_t)(rowbase + 16 * s + lrow) * DD + lkh * 8;
            a[s][0] = *(const bf16x8*)(ab);
            a[s][1] = *(const bf16x8*)(ab + 32);
        }
    }
    __syncthreads();

    for (int k = ks; k < ke; ++k) {
        int nI = I, ntj = tj + 1;
        bool more = (k + 1 < ke);
        if (more) {
            if (ntj == TT) { nI = I + 1; ntj = 2 * nI; }
            const short* bt = ebf + (size_t)ntj * (128 * DD);
            #pragma unroll
            for (int q = 0; q < 4; ++q) {
                int chunk = 2 * q + wsel;
                __builtin_amdgcn_global_load_lds(
                    (gu32_t*)(const void*)(bt + (size_t)srr * DD + chunk * 8),
                    (lu32_t*)(void*)&lbs[cur ^ 1][q * 2048 + w * 512], 16, 0, 0);
            }
        }

        // ---- compute unit (I, tj) from lbs[cur] ----
        int rt = 2 * I + (w >> 1);
        float wgt = (tj == rt) ? 1.0f : ((tj > rt) ? 2.0f : 0.0f);
        if (wgt != 0.0f) {
            int bj = tj * 128;
            const short* lb = lbs[cur];
            float hp = 0.0f;
            #pragma unroll
            for (int t = 0; t < 8; ++t) {
                bf16x8 b0 = *(const bf16x8*)&lb[lkh * 1024 + (t * 16 + lrow) * 8];
                bf16x8 b1 = *(const bf16x8*)&lb[(lkh + 4) * 1024 + (t * 16 + lrow) * 8];
                f32x4 c[4];
                #pragma unroll
                for (int s = 0; s < 4; ++s) {
                    f32x4 z = {0.f, 0.f, 0.f, 0.f};
                    z = __builtin_amdgcn_mfma_f32_16x16x32_bf16(a[s][0], b0, z, 0, 0, 0);
                    z = __builtin_amdgcn_mfma_f32_16x16x32_bf16(a[s][1], b1, z, 0, 0, 0);
                    c[s] = z;
                }
                float mx = fmaxf(fmaxf(c[0][0], c[0][1]), fmaxf(c[0][2], c[0][3]));
                mx = fmaxf(mx, fmaxf(fmaxf(c[1][0], c[1][1]), fmaxf(c[1][2], c[1][3])));
                mx = fmaxf(mx, fmaxf(fmaxf(c[2][0], c[2][1]), fmaxf(c[2][2], c[2][3])));
                mx = fmaxf(mx, fmaxf(fmaxf(c[3][0], c[3][1]), fmaxf(c[3][2], c[3][3])));
                if (__any(mx > SCREEN_T)) {               // rare (~2%)
                    int j = bj + t * 16 + lrow;
                    float vj = vc[j]; int lj = lab[j];
                    #pragma unroll
                    for (int s = 0; s < 4; ++s) {
                        #pragma unroll
                        for (int r = 0; r < 4; ++r) {
                            int i0 = rowbase + 16 * s + lkh * 4 + r;
                            float d2 = fmaf(-2.0f, c[s][r], u[i0] + vj);
                            float d  = sqrtf(fmaxf(d2, 1e-12f));
                            float h  = fmaxf(1.0f - d, 0.0f);
                            if (lab[i0] != lj) hp = fmaf(h, h, hp);
                        }
                    }
                }
            }
            hacc = fmaf(wgt, hp, hacc);
        }

        __syncthreads();            // next buf staged + all readers done
        cur ^= 1;
        if (more && nI != I) {      // band changed: reload A
            rowbase = nI * 256 + w * 64;
            #pragma unroll
            for (int s = 0; s < 4; ++s) {
                const short* ab = ebf + (size_t)(rowbase + 16 * s + lrow) * DD + lkh * 8;
                a[s][0] = *(const bf16x8*)(ab);
                a[s][1] = *(const bf16x8*)(ab + 32);
            }
        }
        I = nI; tj = ntj;
    }

    hacc = wave_sum_f(hacc);
    float* sred = (float*)lbs;      // reuse LDS for final block reduce
    if (lane == 0) sred[w] = hacc;
    __syncthreads();
    if (tid == 0)
        negP[blockIdx.x] = sred[0] + sred[1] + sred[2] + sred[3];
}

// ---------------------------------------------------------------------------
// Kernel 3: final reduction + label histogram -> analytic negative count.
//   n_neg = N^2 - sum_c n_c^2 ;  n_comparisons = N + n_neg
// ---------------------------------------------------------------------------
__global__ __launch_bounds__(256) void reduce_kernel(
    const float* __restrict__ posP, const float* __restrict__ negP,
    const int* __restrict__ lab, float* __restrict__ out) {
    __shared__ unsigned int hist[1024];
    int t = threadIdx.x;
    for (int i = t; i < 1024; i += 256) hist[i] = 0u;
    __syncthreads();
    const int4* lab4 = (const int4*)lab;
    for (int i = t; i < NN / 4; i += 256) {
        int4 v = lab4[i];
        atomicAdd(&hist[v.x & 1023], 1u);
        atomicAdd(&hist[v.y & 1023], 1u);
        atomicAdd(&hist[v.z & 1023], 1u);
        atomicAdd(&hist[v.w & 1023], 1u);
    }
    __syncthreads();

    float ps = 0.f, ns = 0.f;
    unsigned int sqc = 0u;
    const float4* posP4 = (const float4*)posP;
    for (int i = t; i < NPOSB / 4; i += 256) {
        float4 v = posP4[i];
        ps += (v.x + v.y) + (v.z + v.w);
    }
    for (int i = t; i < NBLK; i += 256) ns += negP[i];
    for (int i = t; i < 1024; i += 256) { unsigned int h = hist[i]; sqc += h * h; }

    ps = wave_sum_f(ps);
    ns = wave_sum_f(ns);
    #pragma unroll
    for (int o = 32; o >= 1; o >>= 1) sqc += __shfl_xor(sqc, o);

    __shared__ float sp[4], sn[4];
    __shared__ unsigned int sc[4];
    int w = t >> 6, lane = t & 63;
    if (lane == 0) { sp[w] = ps; sn[w] = ns; sc[w] = sqc; }
    __syncthreads();
    if (t == 0) {
        float pos = sp[0] + sp[1] + sp[2] + sp[3];
        float neg = sn[0] + sn[1] + sn[2] + sn[3];
        unsigned long long s2 = (unsigned long long)sc[0] + sc[1] + sc[2] + sc[3];
        unsigned long long nneg = (unsigned long long)NN * NN - s2;
        float ncomp = (float)((unsigned long long)NN + nneg);
        out[0] = (pos + neg) / ncomp;
    }
}

// ---------------------------------------------------------------------------
// ws layout (bytes):
//   u    @ 0        : 65536
//   vc   @ 65536    : 65536
//   ebf  @ 131072   : 2097152
//   posP @ 2228224  : 16384   (NPOSB=4096 floats)
//   negP @ 2244608  : 4096    (NBLK=1024 floats)
//   total ~2.25 MB
// ---------------------------------------------------------------------------
extern "C" void kernel_launch(void* const* d_in, const int* in_sizes, int n_in,
                              void* d_out, int out_size, void* d_ws, size_t ws_size,
                              hipStream_t stream) {
    const float* emb = (const float*)d_in[0];
    const int* lab   = (const int*)d_in[1];
    const int* pidx  = (const int*)d_in[2];
    float* out = (float*)d_out;
    char* ws = (char*)d_ws;
    float*          u    = (float*)(ws);
    float*          vc   = (float*)(ws + 65536);
    __hip_bfloat16* ebf  = (__hip_bfloat16*)(ws + 131072);
    float*          posP = (float*)(ws + 2228224);
    float*          negP = (float*)(ws + 2244608);

    norm_kernel<<<NPOSB, 256, 0, stream>>>(emb, pidx, u, vc, ebf, posP);
    pair_kernel<<<NBLK, 256, 0, stream>>>((const short*)ebf, u, vc, lab, negP);
    reduce_kernel<<<1, 256, 0, stream>>>(posP, negP, lab, out);
}

// Round 6
// 57.960 us; speedup vs baseline: 1.0632x; 1.0632x over previous
//
#include <hip/hip_runtime.h>
#include <hip/hip_bf16.h>

#define NN 16384
#define DD 64
#define NBI 32                 // 512-row bands
#define NUNITS 2112            // sum_I (128 - 4I), I=0..31
#define NBLK 768
#define NPOSB (NN/4)
#define RING 3
#define SCREEN_T 0.49f         // hinge>0 needs gram > ~0.5-3e-5; margin 1e-2

constexpr float F_EPS_PD   = 1e-6f;
constexpr float F_EPS_NORM = 1e-6f;

using bf16x8 = __attribute__((ext_vector_type(8))) short;
using f32x4  = __attribute__((ext_vector_type(4))) float;
typedef __attribute__((address_space(1))) const unsigned int gu32_t;
typedef __attribute__((address_space(3))) unsigned int       lu32_t;

__device__ __forceinline__ float wave_sum_f(float v) {
    #pragma unroll
    for (int o = 32; o >= 1; o >>= 1) v += __shfl_xor(v, o);
    return v;
}

// unit offset of band I (units are (band, col-tile) with tj in [4I,128))
__device__ __forceinline__ int band_off(int I) { return 2 * I * (65 - I); }

// ---------------------------------------------------------------------------
// Kernel 1: per-row normalize + bf16 copy + u / packed (vc,label) + pos loss.
//   u[i]  = sq_i + 2*eps*s_i
//   vcp[j] = { sq_j - 2*eps*s_j + D*eps*eps , (float)label_j }
// d2 = u_i + vcp[j].x - 2*gram(i,j)
// ---------------------------------------------------------------------------
__global__ __launch_bounds__(256) void norm_kernel(
    const float* __restrict__ emb, const int* __restrict__ pidx,
    const int* __restrict__ lab, float* __restrict__ u,
    float2* __restrict__ vcp, __hip_bfloat16* __restrict__ ebf,
    float* __restrict__ posP) {
    int w    = threadIdx.x >> 6;
    int row  = blockIdx.x * 4 + w;
    int lane = threadIdx.x & 63;
    int j    = pidx[row];
    float x  = emb[(size_t)row * DD + lane];
    float xj = emb[(size_t)j   * DD + lane];

    float n2  = wave_sum_f(x * x);
    float sx  = wave_sum_f(x);
    float n2j = wave_sum_f(xj * xj);
    float sxj = wave_sum_f(xj);
    float dot = wave_sum_f(x * xj);

    float m  = fmaxf(sqrtf(n2),  F_EPS_NORM);
    float mj = fmaxf(sqrtf(n2j), F_EPS_NORM);
    ebf[(size_t)row * DD + lane] = __float2bfloat16(x / m);

    __shared__ float spos[4];
    if (lane == 0) {
        float sq  = n2 / (m * m);
        float sqj = n2j / (mj * mj);
        float s   = sx / m;
        float sj  = sxj / mj;
        float g   = dot / (m * mj);
        u[row] = sq + 2.0f * F_EPS_PD * s;
        vcp[row] = make_float2(
            sq - 2.0f * F_EPS_PD * s + (float)DD * F_EPS_PD * F_EPS_PD,
            (float)lab[row]);
        float d2p = sq + sqj - 2.0f * g + 2.0f * F_EPS_PD * (s - sj)
                  + (float)DD * F_EPS_PD * F_EPS_PD;
        spos[w] = fmaxf(d2p, 0.0f);
    }
    __syncthreads();
    if (threadIdx.x == 0)
        posP[blockIdx.x] = spos[0] + spos[1] + spos[2] + spos[3];
}

// ---------------------------------------------------------------------------
// Staging: 16 KB col-tile -> ring slot, 16 instrs (2 per wave), coalesced
// source with XOR-preswizzle so ds_read is ~bank-free (both-sides rule):
// LDS row r, 16B slot c holds global chunk g = c ^ (r&7).
// instr m = w*2+q covers rows [8m,8m+8); lane l -> row 8m+(l>>3), c = l&7.
// ---------------------------------------------------------------------------
__device__ __forceinline__ void stage_tile(const short* tbase, short* slot,
                                           int w, int lane) {
    int rlo = lane >> 3;
    int g   = (lane & 7) ^ rlo;
    #pragma unroll
    for (int q = 0; q < 2; ++q) {
        int m = w * 2 + q;
        __builtin_amdgcn_global_load_lds(
            (gu32_t*)(const void*)(tbase + (size_t)(8 * m + rlo) * DD + g * 8),
            (lu32_t*)(void*)(slot + m * 512), 16, 0, 0);
    }
}

// ---------------------------------------------------------------------------
// Kernel 2: 8-wave blocks over (512-row band I, 128-col tile tj), tj>=4I.
// Wave w owns 64 rows (4 strips); per tile: 16 ds_read_b128 feed 64 MFMA.
// Counted-vmcnt ring (RING=3, 2-deep prefetch): per iter
//   s_waitcnt vmcnt(2) ; s_barrier ; sched_barrier ; stage(k+2) ; compute(k)
// -> no vmcnt(0) drain in steady state (T4). Segments per band (<=2/block).
// Per-wave weight vs own row-tile rt: diag 1 / upper 2 / lower 0.
// Screen: hinge needs gram > ~0.5; exact math on rare (~4%) path with one
// float2 gather (vc,label). Negative count analytic in reduce_kernel.
// ---------------------------------------------------------------------------
__global__ __launch_bounds__(512, 4) void pair_kernel(
    const short* __restrict__ ebf, const float* __restrict__ u,
    const float2* __restrict__ vcp, float* __restrict__ negP) {
    __shared__ short ring[RING][8192];   // 3 x 16 KB, swizzled row-major
    __shared__ float sred[8];
    int tid  = threadIdx.x;
    int w    = tid >> 6;
    int lane = tid & 63;
    int lrow = lane & 15, lkh = lane >> 4;
    int c0s  = ((lkh)     ^ (lrow & 7)) * 8;   // shorts offset of K[0:32) chunk
    int c1s  = ((lkh + 4) ^ (lrow & 7)) * 8;   // shorts offset of K[32:64)

    int ks = (int)(((long long)blockIdx.x * NUNITS) / NBLK);
    int ke = (int)(((long long)(blockIdx.x + 1) * NUNITS) / NBLK);

    // decode ks -> band I
    int I = (int)((65.0f - sqrtf(4225.0f - 2.0f * (float)ks)) * 0.5f);
    I = I < 0 ? 0 : (I > NBI - 1 ? NBI - 1 : I);
    while (band_off(I) > ks) --I;
    while (I < NBI - 1 && band_off(I + 1) <= ks) ++I;

    float hacc = 0.0f;
    int k0 = ks;
    while (k0 < ke) {
        int bend = band_off(I + 1);
        int n    = (ke < bend ? ke : bend) - k0;
        int tj0  = 4 * I + (k0 - band_off(I));
        int rowbase = I * 512 + w * 64;
        int rt      = 4 * I + (w >> 1);

        // --- segment prologue: A-frags + own-row u/label + prime ring ---
        bf16x8 a[4][2];
        float uo[4][4], lo[4][4];
        #pragma unroll
        for (int s = 0; s < 4; ++s) {
            const short* ab = ebf + (size_t)(rowbase + 16 * s + lrow) * DD + lkh * 8;
            a[s][0] = *(const bf16x8*)(ab);
            a[s][1] = *(const bf16x8*)(ab + 32);
            #pragma unroll
            for (int r = 0; r < 4; ++r) {
                int i0 = rowbase + 16 * s + lkh * 4 + r;
                uo[s][r] = u[i0];
                lo[s][r] = vcp[i0].y;
            }
        }
        int np = n < 2 ? n : 2;
        for (int p = 0; p < np; ++p)
            stage_tile(ebf + (size_t)(tj0 + p) * (128 * DD), &ring[p][0], w, lane);

        for (int k = 0; k < n; ++k) {
            if (k + 1 < n) asm volatile("s_waitcnt vmcnt(2)" ::: "memory");
            else           asm volatile("s_waitcnt vmcnt(0)" ::: "memory");
            __builtin_amdgcn_s_barrier();
            __builtin_amdgcn_sched_barrier(0);
            if (k + 2 < n)
                stage_tile(ebf + (size_t)(tj0 + k + 2) * (128 * DD),
                           &ring[(k + 2) % RING][0], w, lane);

            int tj = tj0 + k;
            float wgt = (tj == rt) ? 1.0f : ((tj > rt) ? 2.0f : 0.0f);
            if (wgt != 0.0f) {
                const short* sl = &ring[k % RING][0];
                int bj = tj * 128;
                float hp = 0.0f;
                #pragma unroll
                for (int t = 0; t < 8; ++t) {
                    const short* rowp = sl + (t * 16 + lrow) * 64;
                    bf16x8 b0 = *(const bf16x8*)(rowp + c0s);
                    bf16x8 b1 = *(const bf16x8*)(rowp + c1s);
                    f32x4 c[4];
                    #pragma unroll
                    for (int s = 0; s < 4; ++s) {
                        f32x4 z = {0.f, 0.f, 0.f, 0.f};
                        z = __builtin_amdgcn_mfma_f32_16x16x32_bf16(a[s][0], b0, z, 0, 0, 0);
                        z = __builtin_amdgcn_mfma_f32_16x16x32_bf16(a[s][1], b1, z, 0, 0, 0);
                        c[s] = z;
                    }
                    float mx = fmaxf(fmaxf(c[0][0], c[0][1]), fmaxf(c[0][2], c[0][3]));
                    mx = fmaxf(mx, fmaxf(fmaxf(c[1][0], c[1][1]), fmaxf(c[1][2], c[1][3])));
                    mx = fmaxf(mx, fmaxf(fmaxf(c[2][0], c[2][1]), fmaxf(c[2][2], c[2][3])));
                    mx = fmaxf(mx, fmaxf(fmaxf(c[3][0], c[3][1]), fmaxf(c[3][2], c[3][3])));
                    if (__any(mx > SCREEN_T)) {            // rare (~4%)
                        float2 vl = vcp[bj + t * 16 + lrow];
                        #pragma unroll
                        for (int s = 0; s < 4; ++s) {
                            #pragma unroll
                            for (int r = 0; r < 4; ++r) {
                                float d2 = fmaf(-2.0f, c[s][r], uo[s][r] + vl.x);
                                float d  = sqrtf(fmaxf(d2, 1e-12f));
                                float h  = fmaxf(1.0f - d, 0.0f);
                                if (lo[s][r] != vl.y) hp = fmaf(h, h, hp);
                            }
                        }
                    }
                }
                hacc = fmaf(wgt, hp, hacc);
            }
        }
        __builtin_amdgcn_s_barrier();   // protect ring reuse across segments
        k0 += n;
        ++I;
    }

    hacc = wave_sum_f(hacc);
    if (lane == 0) sred[w] = hacc;
    __syncthreads();
    if (tid == 0) {
        float tn = 0.f;
        #pragma unroll
        for (int i = 0; i < 8; ++i) tn += sred[i];
        negP[blockIdx.x] = tn;
    }
}

// ---------------------------------------------------------------------------
// Kernel 3: final reduction + label histogram -> analytic negative count.
//   n_neg = N^2 - sum_c n_c^2 ;  n_comparisons = N + n_neg
// ---------------------------------------------------------------------------
__global__ __launch_bounds__(256) void reduce_kernel(
    const float* __restrict__ posP, const float* __restrict__ negP,
    const int* __restrict__ lab, float* __restrict__ out) {
    __shared__ unsigned int hist[1024];
    int t = threadIdx.x;
    for (int i = t; i < 1024; i += 256) hist[i] = 0u;
    __syncthreads();
    const int4* lab4 = (const int4*)lab;
    for (int i = t; i < NN / 4; i += 256) {
        int4 v = lab4[i];
        atomicAdd(&hist[v.x & 1023], 1u);
        atomicAdd(&hist[v.y & 1023], 1u);
        atomicAdd(&hist[v.z & 1023], 1u);
        atomicAdd(&hist[v.w & 1023], 1u);
    }
    __syncthreads();

    float ps = 0.f, ns = 0.f;
    unsigned int sqc = 0u;
    const float4* posP4 = (const float4*)posP;
    for (int i = t; i < NPOSB / 4; i += 256) {
        float4 v = posP4[i];
        ps += (v.x + v.y) + (v.z + v.w);
    }
    for (int i = t; i < NBLK; i += 256) ns += negP[i];
    for (int i = t; i < 1024; i += 256) { unsigned int h = hist[i]; sqc += h * h; }

    ps = wave_sum_f(ps);
    ns = wave_sum_f(ns);
    #pragma unroll
    for (int o = 32; o >= 1; o >>= 1) sqc += __shfl_xor(sqc, o);

    __shared__ float sp[4], sn[4];
    __shared__ unsigned int sc[4];
    int w = t >> 6, lane = t & 63;
    if (lane == 0) { sp[w] = ps; sn[w] = ns; sc[w] = sqc; }
    __syncthreads();
    if (t == 0) {
        float pos = sp[0] + sp[1] + sp[2] + sp[3];
        float neg = sn[0] + sn[1] + sn[2] + sn[3];
        unsigned long long s2 = (unsigned long long)sc[0] + sc[1] + sc[2] + sc[3];
        unsigned long long nneg = (unsigned long long)NN * NN - s2;
        float ncomp = (float)((unsigned long long)NN + nneg);
        out[0] = (pos + neg) / ncomp;
    }
}

// ---------------------------------------------------------------------------
// ws layout (bytes):
//   u    @ 0        : 65536
//   vcp  @ 65536    : 131072  (float2[16384]: {vc, label})
//   ebf  @ 196608   : 2097152
//   posP @ 2293760  : 16384   (NPOSB floats)
//   negP @ 2310144  : 3072    (NBLK floats)
//   total 2313216
// ---------------------------------------------------------------------------
extern "C" void kernel_launch(void* const* d_in, const int* in_sizes, int n_in,
                              void* d_out, int out_size, void* d_ws, size_t ws_size,
                              hipStream_t stream) {
    const float* emb = (const float*)d_in[0];
    const int* lab   = (const int*)d_in[1];
    const int* pidx  = (const int*)d_in[2];
    float* out = (float*)d_out;
    char* ws = (char*)d_ws;
    float*          u    = (float*)(ws);
    float2*         vcp  = (float2*)(ws + 65536);
    __hip_bfloat16* ebf  = (__hip_bfloat16*)(ws + 196608);
    float*          posP = (float*)(ws + 2293760);
    float*          negP = (float*)(ws + 2310144);

    norm_kernel<<<NPOSB, 256, 0, stream>>>(emb, pidx, lab, u, vcp, ebf, posP);
    pair_kernel<<<NBLK, 512, 0, stream>>>((const short*)ebf, u, vcp, negP);
    reduce_kernel<<<1, 256, 0, stream>>>(posP, negP, lab, out);
}